// Round 3
// baseline (1340.817 us; speedup 1.0000x reference)
//
#include <hip/hip_runtime.h>

#define D 128
#define GEMM_ROWS 32
#define BSHIFT 6            // 64 nodes per bucket
#define BNODES 64
#define CAP 1280            // bucket capacity (mean 1024, ~8 sigma slack)
#define CSTRIDE 16          // cursor padding (64B) to spread atomic lines

__device__ __forceinline__ unsigned bfpack2(float a, float b) {
    unsigned ua = __float_as_uint(a); ua = (ua + 0x7FFFu + ((ua >> 16) & 1u)) >> 16;
    unsigned ub = __float_as_uint(b); ub = (ub + 0x7FFFu + ((ub >> 16) & 1u)) >> 16;
    return ua | (ub << 16);
}

// ---------------- GEMM: hb = bf16(x @ W) ----------------
__global__ __launch_bounds__(256) void gemm_kernel(const float* __restrict__ x,
                                                   const float* __restrict__ w,
                                                   unsigned* __restrict__ hb2, int n) {
    __shared__ float wlds[D * D];          // 64 KB
    __shared__ float xlds[GEMM_ROWS * D];  // 16 KB

    const float4* w4 = (const float4*)w;
    float4* wl4 = (float4*)wlds;
    for (int i = threadIdx.x; i < D * D / 4; i += 256) wl4[i] = w4[i];

    int row0 = blockIdx.x * GEMM_ROWS;
    int nrow = n - row0; if (nrow > GEMM_ROWS) nrow = GEMM_ROWS;
    const float4* x4 = (const float4*)(x + (size_t)row0 * D);
    float4* xl4 = (float4*)xlds;
    for (int i = threadIdx.x; i < nrow * D / 4; i += 256) xl4[i] = x4[i];
    __syncthreads();

    int tc = (threadIdx.x & 31) * 4;
    int tr = (threadIdx.x >> 5) * 4;

    float4 a0 = {0.f,0.f,0.f,0.f}, a1 = a0, a2 = a0, a3 = a0;

    #pragma unroll 8
    for (int k = 0; k < D; ++k) {
        float4 wv = *(const float4*)&wlds[k * D + tc];
        float x0 = xlds[(tr + 0) * D + k];
        float x1 = xlds[(tr + 1) * D + k];
        float x2 = xlds[(tr + 2) * D + k];
        float x3 = xlds[(tr + 3) * D + k];
        a0.x += x0 * wv.x; a0.y += x0 * wv.y; a0.z += x0 * wv.z; a0.w += x0 * wv.w;
        a1.x += x1 * wv.x; a1.y += x1 * wv.y; a1.z += x1 * wv.z; a1.w += x1 * wv.w;
        a2.x += x2 * wv.x; a2.y += x2 * wv.y; a2.z += x2 * wv.z; a2.w += x2 * wv.w;
        a3.x += x3 * wv.x; a3.y += x3 * wv.y; a3.z += x3 * wv.z; a3.w += x3 * wv.w;
    }

    // store 4 rows x 4 cols as bf16: uint holds 2 bf16, so 2 uints per row-chunk
    // hb2 layout: row * 64 + col/2
    int cbase = tc >> 1;  // uint index of col tc
    if (row0 + tr + 0 < n) { size_t o = (size_t)(row0+tr+0)*64 + cbase; hb2[o]=bfpack2(a0.x,a0.y); hb2[o+1]=bfpack2(a0.z,a0.w); }
    if (row0 + tr + 1 < n) { size_t o = (size_t)(row0+tr+1)*64 + cbase; hb2[o]=bfpack2(a1.x,a1.y); hb2[o+1]=bfpack2(a1.z,a1.w); }
    if (row0 + tr + 2 < n) { size_t o = (size_t)(row0+tr+2)*64 + cbase; hb2[o]=bfpack2(a2.x,a2.y); hb2[o+1]=bfpack2(a2.z,a2.w); }
    if (row0 + tr + 3 < n) { size_t o = (size_t)(row0+tr+3)*64 + cbase; hb2[o]=bfpack2(a3.x,a3.y); hb2[o+1]=bfpack2(a3.z,a3.w); }
}

// ---------------- bucket fill: packed ((rl<<17)|col, val) ----------------
__global__ __launch_bounds__(256) void fill_kernel(const int* __restrict__ row,
                                                   const int* __restrict__ col,
                                                   const float* __restrict__ ev,
                                                   int* __restrict__ cursor,
                                                   int2* __restrict__ pairs, int e) {
    int i = (blockIdx.x * 256 + threadIdx.x) * 4;
    if (i + 4 <= e) {
        int4 r = *(const int4*)(row + i);
        int4 c = *(const int4*)(col + i);
        float4 v = *(const float4*)(ev + i);
        int b, p;
        b = r.x >> BSHIFT; p = atomicAdd(&cursor[b * CSTRIDE], 1);
        if (p < CAP) pairs[(size_t)b * CAP + p] = make_int2(((r.x & (BNODES-1)) << 17) | c.x, __float_as_int(v.x));
        b = r.y >> BSHIFT; p = atomicAdd(&cursor[b * CSTRIDE], 1);
        if (p < CAP) pairs[(size_t)b * CAP + p] = make_int2(((r.y & (BNODES-1)) << 17) | c.y, __float_as_int(v.y));
        b = r.z >> BSHIFT; p = atomicAdd(&cursor[b * CSTRIDE], 1);
        if (p < CAP) pairs[(size_t)b * CAP + p] = make_int2(((r.z & (BNODES-1)) << 17) | c.z, __float_as_int(v.z));
        b = r.w >> BSHIFT; p = atomicAdd(&cursor[b * CSTRIDE], 1);
        if (p < CAP) pairs[(size_t)b * CAP + p] = make_int2(((r.w & (BNODES-1)) << 17) | c.w, __float_as_int(v.w));
    } else {
        for (; i < e; ++i) {
            int b = row[i] >> BSHIFT;
            int p = atomicAdd(&cursor[b * CSTRIDE], 1);
            if (p < CAP) pairs[(size_t)b * CAP + p] = make_int2(((row[i] & (BNODES-1)) << 17) | col[i], __float_as_int(ev[i]));
        }
    }
}

// ---------------- bucketed gather-reduce with LDS accumulation ----------------
// one block per bucket (64 nodes); acc[64][128] fp32 in LDS (32 KB)
__global__ __launch_bounds__(256) void reduce_kernel(const unsigned* __restrict__ hb2,
                                                     const int2* __restrict__ pairs,
                                                     const int* __restrict__ cursor,
                                                     const float4* __restrict__ bias4,
                                                     float4* __restrict__ out4, int n) {
    __shared__ float acc[BNODES * D];
    int b = blockIdx.x;
    int tid = threadIdx.x;

    float4* a4 = (float4*)acc;
    #pragma unroll
    for (int i = tid; i < BNODES * D / 4; i += 256) a4[i] = make_float4(0.f,0.f,0.f,0.f);
    __syncthreads();

    int cnt = cursor[b * CSTRIDE];
    if (cnt > CAP) cnt = CAP;
    const int2* pb = pairs + (size_t)b * CAP;

    int lane = tid & 63, wid = tid >> 6;

    for (int j = wid * 4; j < cnt; j += 16) {
        int m = cnt - j; if (m > 4) m = 4;     // wave-uniform
        int rl[4]; float vv[4]; float2 hv[4];
        #pragma unroll
        for (int k = 0; k < 4; ++k) {
            if (k < m) {
                int2 p = pb[j + k];
                int c = p.x & 0x1FFFF;
                rl[k] = p.x >> 17;
                vv[k] = __int_as_float(p.y);
                unsigned u = hb2[(size_t)c * 64 + lane];
                hv[k].x = __uint_as_float(u << 16);
                hv[k].y = __uint_as_float(u & 0xFFFF0000u);
            }
        }
        #pragma unroll
        for (int k = 0; k < 4; ++k) {
            if (k < m) {
                atomicAdd(&acc[rl[k] * D + lane * 2 + 0], vv[k] * hv[k].x);
                atomicAdd(&acc[rl[k] * D + lane * 2 + 1], vv[k] * hv[k].y);
            }
        }
    }
    __syncthreads();

    int node0 = b * BNODES;
    int nrow = n - node0; if (nrow > BNODES) nrow = BNODES;
    for (int i = tid; i < nrow * (D / 4); i += 256) {
        int r = i >> 5, c = i & 31;
        float4 a = a4[(size_t)r * 32 + c];
        float4 bv = bias4[c];
        out4[((size_t)(node0 + r)) * 32 + c] = make_float4(a.x + bv.x, a.y + bv.y, a.z + bv.z, a.w + bv.w);
    }
}

extern "C" void kernel_launch(void* const* d_in, const int* in_sizes, int n_in,
                              void* d_out, int out_size, void* d_ws, size_t ws_size,
                              hipStream_t stream) {
    const float* x    = (const float*)d_in[0];
    const float* w    = (const float*)d_in[1];
    const float* bias = (const float*)d_in[2];
    const float* ev   = (const float*)d_in[3];
    const int*   row  = (const int*)d_in[4];
    const int*   col  = (const int*)d_in[5];
    float* out = (float*)d_out;

    int n = in_sizes[0] / D;   // 100000
    int e = in_sizes[3];       // 1600000
    int nb = (n + BNODES - 1) / BNODES;   // 1563 buckets

    // workspace layout
    unsigned* hb2   = (unsigned*)d_ws;                       // n*64 uints (25.6 MB)
    int2*     pairs = (int2*)(hb2 + (size_t)n * 64);         // nb*CAP int2 (16 MB)
    int*      cursor= (int*)(pairs + (size_t)nb * CAP);      // nb*CSTRIDE ints (100 KB)

    hipMemsetAsync(cursor, 0, (size_t)nb * CSTRIDE * sizeof(int), stream);

    gemm_kernel<<<(n + GEMM_ROWS - 1) / GEMM_ROWS, 256, 0, stream>>>(x, w, hb2, n);
    fill_kernel<<<(e + 1023) / 1024, 256, 0, stream>>>(row, col, ev, cursor, pairs, e);
    reduce_kernel<<<nb, 256, 0, stream>>>(hb2, pairs, cursor,
                                          (const float4*)bias, (float4*)out, n);
}

// Round 4
// 257.827 us; speedup vs baseline: 5.2005x; 5.2005x over previous
//
#include <hip/hip_runtime.h>

#define D 128
#define GEMM_ROWS 32
#define BSHIFT 6            // 64 nodes per bucket
#define BNODES 64
#define CAP 1280            // bucket capacity (mean 1024, ~8 sigma slack)
#define CSTRIDE 16          // cursor padding (64B) to spread atomic lines

__device__ __forceinline__ unsigned bfpack2(float a, float b) {
    unsigned ua = __float_as_uint(a); ua = (ua + 0x7FFFu + ((ua >> 16) & 1u)) >> 16;
    unsigned ub = __float_as_uint(b); ub = (ub + 0x7FFFu + ((ub >> 16) & 1u)) >> 16;
    return ua | (ub << 16);
}

// ---------------- GEMM: hb = bf16(x @ W) ----------------
__global__ __launch_bounds__(256) void gemm_kernel(const float* __restrict__ x,
                                                   const float* __restrict__ w,
                                                   unsigned* __restrict__ hb2, int n) {
    __shared__ float wlds[D * D];          // 64 KB
    __shared__ float xlds[GEMM_ROWS * D];  // 16 KB

    const float4* w4 = (const float4*)w;
    float4* wl4 = (float4*)wlds;
    for (int i = threadIdx.x; i < D * D / 4; i += 256) wl4[i] = w4[i];

    int row0 = blockIdx.x * GEMM_ROWS;
    int nrow = n - row0; if (nrow > GEMM_ROWS) nrow = GEMM_ROWS;
    const float4* x4 = (const float4*)(x + (size_t)row0 * D);
    float4* xl4 = (float4*)xlds;
    for (int i = threadIdx.x; i < nrow * D / 4; i += 256) xl4[i] = x4[i];
    __syncthreads();

    int tc = (threadIdx.x & 31) * 4;
    int tr = (threadIdx.x >> 5) * 4;

    float4 a0 = {0.f,0.f,0.f,0.f}, a1 = a0, a2 = a0, a3 = a0;

    #pragma unroll 8
    for (int k = 0; k < D; ++k) {
        float4 wv = *(const float4*)&wlds[k * D + tc];
        float x0 = xlds[(tr + 0) * D + k];
        float x1 = xlds[(tr + 1) * D + k];
        float x2 = xlds[(tr + 2) * D + k];
        float x3 = xlds[(tr + 3) * D + k];
        a0.x += x0 * wv.x; a0.y += x0 * wv.y; a0.z += x0 * wv.z; a0.w += x0 * wv.w;
        a1.x += x1 * wv.x; a1.y += x1 * wv.y; a1.z += x1 * wv.z; a1.w += x1 * wv.w;
        a2.x += x2 * wv.x; a2.y += x2 * wv.y; a2.z += x2 * wv.z; a2.w += x2 * wv.w;
        a3.x += x3 * wv.x; a3.y += x3 * wv.y; a3.z += x3 * wv.z; a3.w += x3 * wv.w;
    }

    int cbase = tc >> 1;
    if (row0 + tr + 0 < n) { size_t o = (size_t)(row0+tr+0)*64 + cbase; hb2[o]=bfpack2(a0.x,a0.y); hb2[o+1]=bfpack2(a0.z,a0.w); }
    if (row0 + tr + 1 < n) { size_t o = (size_t)(row0+tr+1)*64 + cbase; hb2[o]=bfpack2(a1.x,a1.y); hb2[o+1]=bfpack2(a1.z,a1.w); }
    if (row0 + tr + 2 < n) { size_t o = (size_t)(row0+tr+2)*64 + cbase; hb2[o]=bfpack2(a2.x,a2.y); hb2[o+1]=bfpack2(a2.z,a2.w); }
    if (row0 + tr + 3 < n) { size_t o = (size_t)(row0+tr+3)*64 + cbase; hb2[o]=bfpack2(a3.x,a3.y); hb2[o+1]=bfpack2(a3.z,a3.w); }
}

// ---------------- bucket fill: packed ((rl<<17)|col, val) ----------------
__global__ __launch_bounds__(256) void fill_kernel(const int* __restrict__ row,
                                                   const int* __restrict__ col,
                                                   const float* __restrict__ ev,
                                                   int* __restrict__ cursor,
                                                   int2* __restrict__ pairs, int e) {
    int i = (blockIdx.x * 256 + threadIdx.x) * 4;
    if (i + 4 <= e) {
        int4 r = *(const int4*)(row + i);
        int4 c = *(const int4*)(col + i);
        float4 v = *(const float4*)(ev + i);
        int b, p;
        b = r.x >> BSHIFT; p = atomicAdd(&cursor[b * CSTRIDE], 1);
        if (p < CAP) pairs[(size_t)b * CAP + p] = make_int2(((r.x & (BNODES-1)) << 17) | c.x, __float_as_int(v.x));
        b = r.y >> BSHIFT; p = atomicAdd(&cursor[b * CSTRIDE], 1);
        if (p < CAP) pairs[(size_t)b * CAP + p] = make_int2(((r.y & (BNODES-1)) << 17) | c.y, __float_as_int(v.y));
        b = r.z >> BSHIFT; p = atomicAdd(&cursor[b * CSTRIDE], 1);
        if (p < CAP) pairs[(size_t)b * CAP + p] = make_int2(((r.z & (BNODES-1)) << 17) | c.z, __float_as_int(v.z));
        b = r.w >> BSHIFT; p = atomicAdd(&cursor[b * CSTRIDE], 1);
        if (p < CAP) pairs[(size_t)b * CAP + p] = make_int2(((r.w & (BNODES-1)) << 17) | c.w, __float_as_int(v.w));
    } else {
        for (; i < e; ++i) {
            int b = row[i] >> BSHIFT;
            int p = atomicAdd(&cursor[b * CSTRIDE], 1);
            if (p < CAP) pairs[(size_t)b * CAP + p] = make_int2(((row[i] & (BNODES-1)) << 17) | col[i], __float_as_int(ev[i]));
        }
    }
}

// ---------------- bucketed reduce: counting-sort to LDS, register accumulate ----------------
// one block per bucket (64 nodes); sorted pairs in LDS (10 KB); 4 waves,
// each wave owns nodes wid, wid+4, ...; float2 register acc; unroll x8 gathers.
__global__ __launch_bounds__(256) void reduce_kernel(const unsigned* __restrict__ hb2,
                                                     const int2* __restrict__ pairs,
                                                     const int* __restrict__ cursor,
                                                     const float2* __restrict__ bias2,
                                                     float2* __restrict__ out2, int n) {
    __shared__ int2 sp[CAP];          // sorted (col, val)
    __shared__ int hist[BNODES + 1];  // exclusive bin offsets, hist[64] = cnt
    __shared__ int bcur[BNODES];

    int b = blockIdx.x;
    int tid = threadIdx.x;
    int lane = tid & 63, wid = tid >> 6;

    int cnt = cursor[b * CSTRIDE];
    if (cnt > CAP) cnt = CAP;
    const int2* pb = pairs + (size_t)b * CAP;

    if (tid < BNODES) hist[tid] = 0;
    __syncthreads();

    // pass 1: histogram of local-row keys
    for (int j = tid; j < cnt; j += 256) {
        int rl = pb[j].x >> 17;
        atomicAdd(&hist[rl], 1);
    }
    __syncthreads();

    // exclusive scan of 64 bins (wave 0)
    if (tid < 64) {
        int v = hist[tid];
        int s = v;
        #pragma unroll
        for (int d = 1; d < 64; d <<= 1) { int t = __shfl_up(s, d); if (lane >= d) s += t; }
        hist[tid] = s - v;
        bcur[tid] = s - v;
        if (tid == 63) hist[64] = cnt;
    }
    __syncthreads();

    // pass 2: scatter into sorted LDS order (strip the rl key, keep col)
    for (int j = tid; j < cnt; j += 256) {
        int2 p = pb[j];
        int rl = p.x >> 17;
        int pos = atomicAdd(&bcur[rl], 1);
        sp[pos] = make_int2(p.x & 0x1FFFF, p.y);
    }
    __syncthreads();

    // per-node register reduce
    int node0 = b * BNODES;
    for (int r = wid; r < BNODES; r += 4) {
        int node = node0 + r;
        if (node >= n) break;
        int beg = hist[r], end = hist[r + 1];
        float2 acc = {0.f, 0.f};
        int j = beg;
        for (; j + 8 <= end; j += 8) {
            unsigned u[8]; float v[8];
            #pragma unroll
            for (int k = 0; k < 8; ++k) {
                int2 p = sp[j + k];
                v[k] = __int_as_float(p.y);
                u[k] = hb2[(size_t)p.x * 64 + lane];
            }
            #pragma unroll
            for (int k = 0; k < 8; ++k) {
                acc.x += v[k] * __uint_as_float(u[k] << 16);
                acc.y += v[k] * __uint_as_float(u[k] & 0xFFFF0000u);
            }
        }
        for (; j < end; ++j) {
            int2 p = sp[j];
            float v = __int_as_float(p.y);
            unsigned u = hb2[(size_t)p.x * 64 + lane];
            acc.x += v * __uint_as_float(u << 16);
            acc.y += v * __uint_as_float(u & 0xFFFF0000u);
        }
        float2 bb = bias2[lane];
        out2[(size_t)node * 64 + lane] = make_float2(acc.x + bb.x, acc.y + bb.y);
    }
}

extern "C" void kernel_launch(void* const* d_in, const int* in_sizes, int n_in,
                              void* d_out, int out_size, void* d_ws, size_t ws_size,
                              hipStream_t stream) {
    const float* x    = (const float*)d_in[0];
    const float* w    = (const float*)d_in[1];
    const float* bias = (const float*)d_in[2];
    const float* ev   = (const float*)d_in[3];
    const int*   row  = (const int*)d_in[4];
    const int*   col  = (const int*)d_in[5];
    float* out = (float*)d_out;

    int n = in_sizes[0] / D;   // 100000
    int e = in_sizes[3];       // 1600000
    int nb = (n + BNODES - 1) / BNODES;   // 1563 buckets

    // workspace layout
    unsigned* hb2   = (unsigned*)d_ws;                       // n*64 uints (25.6 MB)
    int2*     pairs = (int2*)(hb2 + (size_t)n * 64);         // nb*CAP int2 (16 MB)
    int*      cursor= (int*)(pairs + (size_t)nb * CAP);      // nb*CSTRIDE ints (100 KB)

    hipMemsetAsync(cursor, 0, (size_t)nb * CSTRIDE * sizeof(int), stream);

    gemm_kernel<<<(n + GEMM_ROWS - 1) / GEMM_ROWS, 256, 0, stream>>>(x, w, hb2, n);
    fill_kernel<<<(e + 1023) / 1024, 256, 0, stream>>>(row, col, ev, cursor, pairs, e);
    reduce_kernel<<<nb, 256, 0, stream>>>(hb2, pairs, cursor,
                                          (const float2*)bias, (float2*)out, n);
}

// Round 5
// 228.190 us; speedup vs baseline: 5.8759x; 1.1299x over previous
//
#include <hip/hip_runtime.h>

#define D 128
#define GEMM_ROWS 32
#define BSHIFT 6            // 64 nodes per bucket
#define BNODES 64
#define NXCD 8
#define SUBCAP 256          // per-(bucket,xcd) capacity (mean 128, >10 sigma)
#define CAP 1280            // total per-bucket LDS sort capacity (mean 1024)
#define CSTRIDE 16          // cursor padding (64B): one line per (bucket,xcd)

__device__ __forceinline__ int get_xcc() {
    int v;
    asm volatile("s_getreg_b32 %0, hwreg(HW_REG_XCC_ID)" : "=s"(v));
    return v & (NXCD - 1);
}

__device__ __forceinline__ unsigned bfpack2(float a, float b) {
    unsigned ua = __float_as_uint(a); ua = (ua + 0x7FFFu + ((ua >> 16) & 1u)) >> 16;
    unsigned ub = __float_as_uint(b); ub = (ub + 0x7FFFu + ((ub >> 16) & 1u)) >> 16;
    return ua | (ub << 16);
}

// ---------------- GEMM: hb = bf16(x @ W) ----------------
__global__ __launch_bounds__(256) void gemm_kernel(const float* __restrict__ x,
                                                   const float* __restrict__ w,
                                                   unsigned* __restrict__ hb2, int n) {
    __shared__ float wlds[D * D];          // 64 KB
    __shared__ float xlds[GEMM_ROWS * D];  // 16 KB

    const float4* w4 = (const float4*)w;
    float4* wl4 = (float4*)wlds;
    for (int i = threadIdx.x; i < D * D / 4; i += 256) wl4[i] = w4[i];

    int row0 = blockIdx.x * GEMM_ROWS;
    int nrow = n - row0; if (nrow > GEMM_ROWS) nrow = GEMM_ROWS;
    const float4* x4 = (const float4*)(x + (size_t)row0 * D);
    float4* xl4 = (float4*)xlds;
    for (int i = threadIdx.x; i < nrow * D / 4; i += 256) xl4[i] = x4[i];
    __syncthreads();

    int tc = (threadIdx.x & 31) * 4;
    int tr = (threadIdx.x >> 5) * 4;

    float4 a0 = {0.f,0.f,0.f,0.f}, a1 = a0, a2 = a0, a3 = a0;

    #pragma unroll 8
    for (int k = 0; k < D; ++k) {
        float4 wv = *(const float4*)&wlds[k * D + tc];
        float x0 = xlds[(tr + 0) * D + k];
        float x1 = xlds[(tr + 1) * D + k];
        float x2 = xlds[(tr + 2) * D + k];
        float x3 = xlds[(tr + 3) * D + k];
        a0.x += x0 * wv.x; a0.y += x0 * wv.y; a0.z += x0 * wv.z; a0.w += x0 * wv.w;
        a1.x += x1 * wv.x; a1.y += x1 * wv.y; a1.z += x1 * wv.z; a1.w += x1 * wv.w;
        a2.x += x2 * wv.x; a2.y += x2 * wv.y; a2.z += x2 * wv.z; a2.w += x2 * wv.w;
        a3.x += x3 * wv.x; a3.y += x3 * wv.y; a3.z += x3 * wv.z; a3.w += x3 * wv.w;
    }

    int cbase = tc >> 1;
    if (row0 + tr + 0 < n) { size_t o = (size_t)(row0+tr+0)*64 + cbase; hb2[o]=bfpack2(a0.x,a0.y); hb2[o+1]=bfpack2(a0.z,a0.w); }
    if (row0 + tr + 1 < n) { size_t o = (size_t)(row0+tr+1)*64 + cbase; hb2[o]=bfpack2(a1.x,a1.y); hb2[o+1]=bfpack2(a1.z,a1.w); }
    if (row0 + tr + 2 < n) { size_t o = (size_t)(row0+tr+2)*64 + cbase; hb2[o]=bfpack2(a2.x,a2.y); hb2[o+1]=bfpack2(a2.z,a2.w); }
    if (row0 + tr + 3 < n) { size_t o = (size_t)(row0+tr+3)*64 + cbase; hb2[o]=bfpack2(a3.x,a3.y); hb2[o+1]=bfpack2(a3.z,a3.w); }
}

// ---------------- bucket fill: XCD-private sub-buckets ----------------
__global__ __launch_bounds__(256) void fill_kernel(const int* __restrict__ row,
                                                   const int* __restrict__ col,
                                                   const float* __restrict__ ev,
                                                   int* __restrict__ cursor,
                                                   int2* __restrict__ pairs, int e) {
    int xcc = get_xcc();   // wave-uniform, block-uniform
    int i = (blockIdx.x * 256 + threadIdx.x) * 4;
    if (i + 4 <= e) {
        int4 r = *(const int4*)(row + i);
        int4 c = *(const int4*)(col + i);
        float4 v = *(const float4*)(ev + i);
        int sb, p;
        sb = (r.x >> BSHIFT) * NXCD + xcc; p = atomicAdd(&cursor[sb * CSTRIDE], 1);
        if (p < SUBCAP) pairs[(size_t)sb * SUBCAP + p] = make_int2(((r.x & (BNODES-1)) << 17) | c.x, __float_as_int(v.x));
        sb = (r.y >> BSHIFT) * NXCD + xcc; p = atomicAdd(&cursor[sb * CSTRIDE], 1);
        if (p < SUBCAP) pairs[(size_t)sb * SUBCAP + p] = make_int2(((r.y & (BNODES-1)) << 17) | c.y, __float_as_int(v.y));
        sb = (r.z >> BSHIFT) * NXCD + xcc; p = atomicAdd(&cursor[sb * CSTRIDE], 1);
        if (p < SUBCAP) pairs[(size_t)sb * SUBCAP + p] = make_int2(((r.z & (BNODES-1)) << 17) | c.z, __float_as_int(v.z));
        sb = (r.w >> BSHIFT) * NXCD + xcc; p = atomicAdd(&cursor[sb * CSTRIDE], 1);
        if (p < SUBCAP) pairs[(size_t)sb * SUBCAP + p] = make_int2(((r.w & (BNODES-1)) << 17) | c.w, __float_as_int(v.w));
    } else {
        for (; i < e; ++i) {
            int sb = (row[i] >> BSHIFT) * NXCD + xcc;
            int p = atomicAdd(&cursor[sb * CSTRIDE], 1);
            if (p < SUBCAP) pairs[(size_t)sb * SUBCAP + p] = make_int2(((row[i] & (BNODES-1)) << 17) | col[i], __float_as_int(ev[i]));
        }
    }
}

// ---------------- bucketed reduce: counting-sort to LDS, register accumulate ----------------
__global__ __launch_bounds__(256) void reduce_kernel(const unsigned* __restrict__ hb2,
                                                     const int2* __restrict__ pairs,
                                                     const int* __restrict__ cursor,
                                                     const float2* __restrict__ bias2,
                                                     float2* __restrict__ out2, int n) {
    __shared__ int2 sp[CAP];          // sorted (col, val)
    __shared__ int hist[BNODES + 1];  // exclusive bin offsets
    __shared__ int bcur[BNODES];

    int b = blockIdx.x;
    int tid = threadIdx.x;
    int lane = tid & 63, wid = tid >> 6;

    int scnt[NXCD]; int total = 0;
    #pragma unroll
    for (int s = 0; s < NXCD; ++s) {
        int c = cursor[(b * NXCD + s) * CSTRIDE];
        scnt[s] = c > SUBCAP ? SUBCAP : c;
        total += scnt[s];
    }

    if (tid < BNODES) hist[tid] = 0;
    __syncthreads();

    // pass 1: histogram of local-row keys across 8 sub-buckets
    #pragma unroll
    for (int s = 0; s < NXCD; ++s) {
        const int2* pb = pairs + (size_t)(b * NXCD + s) * SUBCAP;
        for (int j = tid; j < scnt[s]; j += 256) atomicAdd(&hist[pb[j].x >> 17], 1);
    }
    __syncthreads();

    // exclusive scan of 64 bins (wave 0)
    if (tid < 64) {
        int v = hist[tid];
        int s = v;
        #pragma unroll
        for (int d = 1; d < 64; d <<= 1) { int t = __shfl_up(s, d); if (lane >= d) s += t; }
        hist[tid] = s - v;
        bcur[tid] = s - v;
        if (tid == 63) hist[64] = total > CAP ? CAP : total;
    }
    __syncthreads();

    // pass 2: scatter into sorted LDS order
    #pragma unroll
    for (int s = 0; s < NXCD; ++s) {
        const int2* pb = pairs + (size_t)(b * NXCD + s) * SUBCAP;
        for (int j = tid; j < scnt[s]; j += 256) {
            int2 p = pb[j];
            int rl = p.x >> 17;
            int pos = atomicAdd(&bcur[rl], 1);
            if (pos < CAP) sp[pos] = make_int2(p.x & 0x1FFFF, p.y);
        }
    }
    __syncthreads();

    // per-node register reduce
    int node0 = b * BNODES;
    for (int r = wid; r < BNODES; r += 4) {
        int node = node0 + r;
        if (node >= n) break;
        int beg = hist[r], end = hist[r + 1];
        if (beg > CAP) beg = CAP;
        if (end > CAP) end = CAP;
        float2 acc = {0.f, 0.f};
        int j = beg;
        for (; j + 8 <= end; j += 8) {
            unsigned u[8]; float v[8];
            #pragma unroll
            for (int k = 0; k < 8; ++k) {
                int2 p = sp[j + k];
                v[k] = __int_as_float(p.y);
                u[k] = hb2[(size_t)p.x * 64 + lane];
            }
            #pragma unroll
            for (int k = 0; k < 8; ++k) {
                acc.x += v[k] * __uint_as_float(u[k] << 16);
                acc.y += v[k] * __uint_as_float(u[k] & 0xFFFF0000u);
            }
        }
        for (; j < end; ++j) {
            int2 p = sp[j];
            float v = __int_as_float(p.y);
            unsigned u = hb2[(size_t)p.x * 64 + lane];
            acc.x += v * __uint_as_float(u << 16);
            acc.y += v * __uint_as_float(u & 0xFFFF0000u);
        }
        float2 bb = bias2[lane];
        out2[(size_t)node * 64 + lane] = make_float2(acc.x + bb.x, acc.y + bb.y);
    }
}

extern "C" void kernel_launch(void* const* d_in, const int* in_sizes, int n_in,
                              void* d_out, int out_size, void* d_ws, size_t ws_size,
                              hipStream_t stream) {
    const float* x    = (const float*)d_in[0];
    const float* w    = (const float*)d_in[1];
    const float* bias = (const float*)d_in[2];
    const float* ev   = (const float*)d_in[3];
    const int*   row  = (const int*)d_in[4];
    const int*   col  = (const int*)d_in[5];
    float* out = (float*)d_out;

    int n = in_sizes[0] / D;   // 100000
    int e = in_sizes[3];       // 1600000
    int nb = (n + BNODES - 1) / BNODES;   // 1563 buckets

    // workspace layout
    unsigned* hb2   = (unsigned*)d_ws;                            // n*64 uints (25.6 MB)
    int2*     pairs = (int2*)(hb2 + (size_t)n * 64);              // nb*8*SUBCAP int2 (25.6 MB)
    int*      cursor= (int*)(pairs + (size_t)nb * NXCD * SUBCAP); // nb*8*CSTRIDE ints (800 KB)

    hipMemsetAsync(cursor, 0, (size_t)nb * NXCD * CSTRIDE * sizeof(int), stream);

    gemm_kernel<<<(n + GEMM_ROWS - 1) / GEMM_ROWS, 256, 0, stream>>>(x, w, hb2, n);
    fill_kernel<<<(e + 1023) / 1024, 256, 0, stream>>>(row, col, ev, cursor, pairs, e);
    reduce_kernel<<<nb, 256, 0, stream>>>(hb2, pairs, cursor,
                                          (const float2*)bias, (float2*)out, n);
}

// Round 6
// 208.979 us; speedup vs baseline: 6.4160x; 1.0919x over previous
//
#include <hip/hip_runtime.h>

#define D 128
#define BSHIFT 6            // 64 nodes per bucket
#define BNODES 64
#define NXCD 8
#define SUBCAP 256          // per-(bucket,xcd) capacity (mean 128, >10 sigma)
#define CAP 1280            // total per-bucket LDS sort capacity (mean 1024)
#define CSTRIDE 16          // cursor padding (64B): one line per (bucket,xcd)

typedef __attribute__((ext_vector_type(8))) short bf16x8;
typedef __attribute__((ext_vector_type(4))) float f32x4;

__device__ __forceinline__ int get_xcc() {
    int v;
    asm volatile("s_getreg_b32 %0, hwreg(HW_REG_XCC_ID)" : "=s"(v));
    return v & (NXCD - 1);
}

__device__ __forceinline__ unsigned short bfrne(float f) {
    unsigned u = __float_as_uint(f);
    return (unsigned short)((u + 0x7FFFu + ((u >> 16) & 1u)) >> 16);
}

// ---------------- W prep: wt_hi/wt_lo[c][k] = bf16 hi/lo of W[k][c] ----------------
__global__ __launch_bounds__(256) void wprep_kernel(const float* __restrict__ w,
                                                    unsigned short* __restrict__ wt_hi,
                                                    unsigned short* __restrict__ wt_lo) {
    int t = blockIdx.x * 256 + threadIdx.x;   // t = c*128 + k
    int c = t >> 7, k = t & 127;
    float v = w[k * D + c];
    unsigned short hi = bfrne(v);
    float hf = __uint_as_float((unsigned)hi << 16);
    wt_hi[t] = hi;
    wt_lo[t] = bfrne(v - hf);
}

// ---------------- GEMM: hb = bf16(x @ W) via split-bf16 MFMA ----------------
// block = 4 waves, 64 rows; wave: 16 rows x 128 cols, K=128 in 4 steps.
__global__ __launch_bounds__(256) void gemm_kernel(const float* __restrict__ x,
                                                   const unsigned short* __restrict__ wt_hi,
                                                   const unsigned short* __restrict__ wt_lo,
                                                   unsigned* __restrict__ hb2, int n) {
    int wid = threadIdx.x >> 6, lane = threadIdx.x & 63;
    int lr = lane & 15, lg = lane >> 4;      // A-row / k-group (loads); C-col (stores)
    int r0 = blockIdx.x * 64 + wid * 16;

    f32x4 acc[8];
    #pragma unroll
    for (int ct = 0; ct < 8; ++ct) acc[ct] = (f32x4){0.f, 0.f, 0.f, 0.f};

    bool rowok = (r0 + lr) < n;
    const float* xrow = x + (size_t)(r0 + lr) * D + lg * 8;

    #pragma unroll
    for (int ks = 0; ks < 4; ++ks) {
        float xv[8];
        if (rowok) {
            float4 a = *(const float4*)(xrow + ks * 32);
            float4 b = *(const float4*)(xrow + ks * 32 + 4);
            xv[0]=a.x; xv[1]=a.y; xv[2]=a.z; xv[3]=a.w;
            xv[4]=b.x; xv[5]=b.y; xv[6]=b.z; xv[7]=b.w;
        } else {
            #pragma unroll
            for (int j = 0; j < 8; ++j) xv[j] = 0.f;
        }
        bf16x8 ahi, alo;
        #pragma unroll
        for (int j = 0; j < 8; ++j) {
            unsigned short h = bfrne(xv[j]);
            ahi[j] = (short)h;
            alo[j] = (short)bfrne(xv[j] - __uint_as_float((unsigned)h << 16));
        }
        #pragma unroll
        for (int ct = 0; ct < 8; ++ct) {
            size_t bo = (size_t)(ct * 16 + lr) * D + ks * 32 + lg * 8;
            bf16x8 bhi = *(const bf16x8*)(wt_hi + bo);
            bf16x8 blo = *(const bf16x8*)(wt_lo + bo);
            acc[ct] = __builtin_amdgcn_mfma_f32_16x16x32_bf16(ahi, bhi, acc[ct], 0, 0, 0);
            acc[ct] = __builtin_amdgcn_mfma_f32_16x16x32_bf16(alo, bhi, acc[ct], 0, 0, 0);
            acc[ct] = __builtin_amdgcn_mfma_f32_16x16x32_bf16(ahi, blo, acc[ct], 0, 0, 0);
        }
    }

    // C/D layout: col = lane&15, row = (lane>>4)*4 + reg  [m89-verified]
    unsigned short* hbu = (unsigned short*)hb2;
    #pragma unroll
    for (int ct = 0; ct < 8; ++ct) {
        #pragma unroll
        for (int reg = 0; reg < 4; ++reg) {
            int rr = r0 + lg * 4 + reg;
            if (rr < n) hbu[(size_t)rr * D + ct * 16 + lr] = bfrne(acc[ct][reg]);
        }
    }
}

// ---------------- bucket fill: XCD-private sub-buckets ----------------
__global__ __launch_bounds__(256) void fill_kernel(const int* __restrict__ row,
                                                   const int* __restrict__ col,
                                                   const float* __restrict__ ev,
                                                   int* __restrict__ cursor,
                                                   int2* __restrict__ pairs, int e) {
    int xcc = get_xcc();   // block-uniform
    int i = (blockIdx.x * 256 + threadIdx.x) * 4;
    if (i + 4 <= e) {
        int4 r = *(const int4*)(row + i);
        int4 c = *(const int4*)(col + i);
        float4 v = *(const float4*)(ev + i);
        int sb, p;
        sb = (r.x >> BSHIFT) * NXCD + xcc; p = atomicAdd(&cursor[sb * CSTRIDE], 1);
        if (p < SUBCAP) pairs[(size_t)sb * SUBCAP + p] = make_int2(((r.x & (BNODES-1)) << 17) | c.x, __float_as_int(v.x));
        sb = (r.y >> BSHIFT) * NXCD + xcc; p = atomicAdd(&cursor[sb * CSTRIDE], 1);
        if (p < SUBCAP) pairs[(size_t)sb * SUBCAP + p] = make_int2(((r.y & (BNODES-1)) << 17) | c.y, __float_as_int(v.y));
        sb = (r.z >> BSHIFT) * NXCD + xcc; p = atomicAdd(&cursor[sb * CSTRIDE], 1);
        if (p < SUBCAP) pairs[(size_t)sb * SUBCAP + p] = make_int2(((r.z & (BNODES-1)) << 17) | c.z, __float_as_int(v.z));
        sb = (r.w >> BSHIFT) * NXCD + xcc; p = atomicAdd(&cursor[sb * CSTRIDE], 1);
        if (p < SUBCAP) pairs[(size_t)sb * SUBCAP + p] = make_int2(((r.w & (BNODES-1)) << 17) | c.w, __float_as_int(v.w));
    } else {
        for (; i < e; ++i) {
            int sb = (row[i] >> BSHIFT) * NXCD + xcc;
            int p = atomicAdd(&cursor[sb * CSTRIDE], 1);
            if (p < SUBCAP) pairs[(size_t)sb * SUBCAP + p] = make_int2(((row[i] & (BNODES-1)) << 17) | col[i], __float_as_int(ev[i]));
        }
    }
}

// ---------------- bucketed reduce: counting-sort to LDS, register accumulate ----------------
__global__ __launch_bounds__(256) void reduce_kernel(const unsigned* __restrict__ hb2,
                                                     const int2* __restrict__ pairs,
                                                     const int* __restrict__ cursor,
                                                     const float2* __restrict__ bias2,
                                                     float2* __restrict__ out2, int n) {
    __shared__ int2 sp[CAP];          // sorted (col, val)
    __shared__ int hist[BNODES + 1];  // exclusive bin offsets
    __shared__ int bcur[BNODES];

    int b = blockIdx.x;
    int tid = threadIdx.x;
    int lane = tid & 63, wid = tid >> 6;

    int scnt[NXCD]; int total = 0;
    #pragma unroll
    for (int s = 0; s < NXCD; ++s) {
        int c = cursor[(b * NXCD + s) * CSTRIDE];
        scnt[s] = c > SUBCAP ? SUBCAP : c;
        total += scnt[s];
    }

    if (tid < BNODES) hist[tid] = 0;
    __syncthreads();

    // pass 1: histogram of local-row keys across 8 sub-buckets
    #pragma unroll
    for (int s = 0; s < NXCD; ++s) {
        const int2* pb = pairs + (size_t)(b * NXCD + s) * SUBCAP;
        for (int j = tid; j < scnt[s]; j += 256) atomicAdd(&hist[pb[j].x >> 17], 1);
    }
    __syncthreads();

    // exclusive scan of 64 bins (wave 0)
    if (tid < 64) {
        int v = hist[tid];
        int s = v;
        #pragma unroll
        for (int d = 1; d < 64; d <<= 1) { int t = __shfl_up(s, d); if (lane >= d) s += t; }
        hist[tid] = s - v;
        bcur[tid] = s - v;
        if (tid == 63) hist[64] = total > CAP ? CAP : total;
    }
    __syncthreads();

    // pass 2: scatter into sorted LDS order
    #pragma unroll
    for (int s = 0; s < NXCD; ++s) {
        const int2* pb = pairs + (size_t)(b * NXCD + s) * SUBCAP;
        for (int j = tid; j < scnt[s]; j += 256) {
            int2 p = pb[j];
            int rl = p.x >> 17;
            int pos = atomicAdd(&bcur[rl], 1);
            if (pos < CAP) sp[pos] = make_int2(p.x & 0x1FFFF, p.y);
        }
    }
    __syncthreads();

    // per-node register reduce
    int node0 = b * BNODES;
    for (int r = wid; r < BNODES; r += 4) {
        int node = node0 + r;
        if (node >= n) break;
        int beg = hist[r], end = hist[r + 1];
        if (beg > CAP) beg = CAP;
        if (end > CAP) end = CAP;
        float2 acc = {0.f, 0.f};
        int j = beg;
        for (; j + 8 <= end; j += 8) {
            unsigned u[8]; float v[8];
            #pragma unroll
            for (int k = 0; k < 8; ++k) {
                int2 p = sp[j + k];
                v[k] = __int_as_float(p.y);
                u[k] = hb2[(size_t)p.x * 64 + lane];
            }
            #pragma unroll
            for (int k = 0; k < 8; ++k) {
                acc.x += v[k] * __uint_as_float(u[k] << 16);
                acc.y += v[k] * __uint_as_float(u[k] & 0xFFFF0000u);
            }
        }
        for (; j < end; ++j) {
            int2 p = sp[j];
            float v = __int_as_float(p.y);
            unsigned u = hb2[(size_t)p.x * 64 + lane];
            acc.x += v * __uint_as_float(u << 16);
            acc.y += v * __uint_as_float(u & 0xFFFF0000u);
        }
        float2 bb = bias2[lane];
        out2[(size_t)node * 64 + lane] = make_float2(acc.x + bb.x, acc.y + bb.y);
    }
}

extern "C" void kernel_launch(void* const* d_in, const int* in_sizes, int n_in,
                              void* d_out, int out_size, void* d_ws, size_t ws_size,
                              hipStream_t stream) {
    const float* x    = (const float*)d_in[0];
    const float* w    = (const float*)d_in[1];
    const float* bias = (const float*)d_in[2];
    const float* ev   = (const float*)d_in[3];
    const int*   row  = (const int*)d_in[4];
    const int*   col  = (const int*)d_in[5];
    float* out = (float*)d_out;

    int n = in_sizes[0] / D;   // 100000
    int e = in_sizes[3];       // 1600000
    int nb = (n + BNODES - 1) / BNODES;   // 1563 buckets

    // workspace layout
    unsigned* hb2    = (unsigned*)d_ws;                            // n*64 uints (25.6 MB)
    int2*     pairs  = (int2*)(hb2 + (size_t)n * 64);              // nb*8*SUBCAP int2 (25.6 MB)
    int*      cursor = (int*)(pairs + (size_t)nb * NXCD * SUBCAP); // nb*8*CSTRIDE ints (800 KB)
    unsigned short* wt_hi = (unsigned short*)(cursor + (size_t)nb * NXCD * CSTRIDE); // 32 KB
    unsigned short* wt_lo = wt_hi + D * D;                                            // 32 KB

    hipMemsetAsync(cursor, 0, (size_t)nb * NXCD * CSTRIDE * sizeof(int), stream);

    wprep_kernel<<<(D * D) / 256, 256, 0, stream>>>(w, wt_hi, wt_lo);
    gemm_kernel<<<(n + 63) / 64, 256, 0, stream>>>(x, wt_hi, wt_lo, hb2, n);
    fill_kernel<<<(e + 1023) / 1024, 256, 0, stream>>>(row, col, ev, cursor, pairs, e);
    reduce_kernel<<<nb, 256, 0, stream>>>(hb2, pairs, cursor,
                                          (const float2*)bias, (float2*)out, n);
}

// Round 8
// 183.737 us; speedup vs baseline: 7.2975x; 1.1374x over previous
//
#include <hip/hip_runtime.h>

#define D 128
#define GR 64               // GEMM rows per block
#define BSHIFT 6            // 64 nodes per bucket
#define BNODES 64
#define NXCD 8
#define SUBCAP 256          // per-(bucket,xcd) capacity (mean 128, >10 sigma)
#define CAP 1280            // total per-bucket LDS sort capacity (mean 1024)
#define CSTRIDE 16          // cursor padding (64B): one line per (bucket,xcd)

typedef __attribute__((ext_vector_type(8))) short bf16x8;
typedef __attribute__((ext_vector_type(4))) float f32x4;
typedef __attribute__((ext_vector_type(2))) float f32x2;
typedef __attribute__((ext_vector_type(4))) int   i32x4;
typedef __attribute__((ext_vector_type(4))) unsigned short u16x4;

__device__ __forceinline__ int get_xcc() {
    int v;
    asm volatile("s_getreg_b32 %0, hwreg(HW_REG_XCC_ID)" : "=s"(v));
    return v & (NXCD - 1);
}

__device__ __forceinline__ unsigned short bfrne(float f) {
    unsigned u = __float_as_uint(f);
    return (unsigned short)((u + 0x7FFFu + ((u >> 16) & 1u)) >> 16);
}

// ---------------- W prep: wt_hi/wt_lo[c][k] = bf16 hi/lo of W[k][c] ----------------
__global__ __launch_bounds__(256) void wprep_kernel(const float* __restrict__ w,
                                                    unsigned short* __restrict__ wt_hi,
                                                    unsigned short* __restrict__ wt_lo) {
    int t = blockIdx.x * 256 + threadIdx.x;   // t = c*128 + k
    int c = t >> 7, k = t & 127;
    float v = w[k * D + c];
    unsigned short hi = bfrne(v);
    float hf = __uint_as_float((unsigned)hi << 16);
    wt_hi[t] = hi;
    wt_lo[t] = bfrne(v - hf);
}

// ---------------- GEMM: hb = bf16(x @ W) via split-bf16 MFMA ----------------
// 4 waves/block, 64 rows/block. Wave w owns 32 cols (ct = 2w, 2w+1) and holds
// its 16 B-fragments in registers (loaded once). x-tile staged in LDS as
// pre-converted bf16 hi/lo, XOR-swizzled against bank conflicts.
__global__ __launch_bounds__(256) void gemm_kernel(const float* __restrict__ x,
                                                   const unsigned short* __restrict__ wt_hi,
                                                   const unsigned short* __restrict__ wt_lo,
                                                   unsigned* __restrict__ hb2, int n) {
    __shared__ __align__(16) unsigned short ah[GR * D];  // 16 KB, swizzled
    __shared__ __align__(16) unsigned short al[GR * D];  // 16 KB, swizzled

    int tid = threadIdx.x;
    int wid = tid >> 6, lane = tid & 63;
    int lr = lane & 15, lg = lane >> 4;
    int r0 = blockIdx.x * GR;

    // ---- stage x-tile: convert fp32 -> bf16 hi/lo once, swizzled LDS write ----
    char* ahb = (char*)ah;
    char* alb = (char*)al;
    #pragma unroll
    for (int i = 0; i < 8; ++i) {
        int fe = (i << 10) + (tid << 2);      // flat element in 64x128 tile
        int r = fe >> 7, k = fe & 127;
        f32x4 v = (f32x4){0.f, 0.f, 0.f, 0.f};
        if (r0 + r < n) v = __builtin_nontemporal_load((const f32x4*)(x + (size_t)(r0 + r) * D + k));
        u16x4 h, l;
        #pragma unroll
        for (int j = 0; j < 4; ++j) {
            unsigned short t0 = bfrne(v[j]);
            h[j] = t0;
            l[j] = bfrne(v[j] - __uint_as_float((unsigned)t0 << 16));
        }
        int soff = (r << 8) + (((k << 1)) ^ ((r & 7) << 4));
        *(u16x4*)(ahb + soff) = h;
        *(u16x4*)(alb + soff) = l;
    }

    // ---- preload this wave's 16 B-fragments (32 cols) ----
    int ctb = wid * 2;
    bf16x8 Bh[2][4], Bl[2][4];
    #pragma unroll
    for (int c2 = 0; c2 < 2; ++c2) {
        #pragma unroll
        for (int ks = 0; ks < 4; ++ks) {
            size_t bo = (size_t)((ctb + c2) * 16 + lr) * D + ks * 32 + lg * 8;
            Bh[c2][ks] = *(const bf16x8*)(wt_hi + bo);
            Bl[c2][ks] = *(const bf16x8*)(wt_lo + bo);
        }
    }
    __syncthreads();

    // ---- MFMA main: 4 row-tiles x 4 k-steps x 2 col-tiles x 3 ----
    f32x4 acc[4][2];
    #pragma unroll
    for (int rt = 0; rt < 4; ++rt)
        #pragma unroll
        for (int c2 = 0; c2 < 2; ++c2) acc[rt][c2] = (f32x4){0.f, 0.f, 0.f, 0.f};

    #pragma unroll
    for (int rt = 0; rt < 4; ++rt) {
        int row = rt * 16 + lr;
        int rbase = (row << 8);
        int rx = (row & 7) << 4;
        #pragma unroll
        for (int ks = 0; ks < 4; ++ks) {
            int kb = (ks << 6) + (lg << 4);
            int addr = rbase + (kb ^ rx);
            bf16x8 Ah = *(const bf16x8*)(ahb + addr);
            bf16x8 Al = *(const bf16x8*)(alb + addr);
            #pragma unroll
            for (int c2 = 0; c2 < 2; ++c2) {
                acc[rt][c2] = __builtin_amdgcn_mfma_f32_16x16x32_bf16(Ah, Bh[c2][ks], acc[rt][c2], 0, 0, 0);
                acc[rt][c2] = __builtin_amdgcn_mfma_f32_16x16x32_bf16(Al, Bh[c2][ks], acc[rt][c2], 0, 0, 0);
                acc[rt][c2] = __builtin_amdgcn_mfma_f32_16x16x32_bf16(Ah, Bl[c2][ks], acc[rt][c2], 0, 0, 0);
            }
        }
    }

    // ---- epilogue: C/D layout col = lane&15, row = (lane>>4)*4 + reg ----
    unsigned short* hbu = (unsigned short*)hb2;
    #pragma unroll
    for (int rt = 0; rt < 4; ++rt) {
        #pragma unroll
        for (int c2 = 0; c2 < 2; ++c2) {
            #pragma unroll
            for (int reg = 0; reg < 4; ++reg) {
                int rr = r0 + rt * 16 + lg * 4 + reg;
                if (rr < n) hbu[(size_t)rr * D + (ctb + c2) * 16 + lr] = bfrne(acc[rt][c2][reg]);
            }
        }
    }
}

// ---------------- bucket fill: XCD-private sub-buckets, nt streaming reads ----------------
__global__ __launch_bounds__(256) void fill_kernel(const int* __restrict__ row,
                                                   const int* __restrict__ col,
                                                   const float* __restrict__ ev,
                                                   int* __restrict__ cursor,
                                                   int2* __restrict__ pairs, int e) {
    int xcc = get_xcc();   // block-uniform
    int i = (blockIdx.x * 256 + threadIdx.x) * 4;
    if (i + 4 <= e) {
        i32x4 r = __builtin_nontemporal_load((const i32x4*)(row + i));
        i32x4 c = __builtin_nontemporal_load((const i32x4*)(col + i));
        f32x4 v = __builtin_nontemporal_load((const f32x4*)(ev + i));
        #pragma unroll
        for (int k = 0; k < 4; ++k) {
            int sb = (r[k] >> BSHIFT) * NXCD + xcc;
            int p = atomicAdd(&cursor[sb * CSTRIDE], 1);
            if (p < SUBCAP) pairs[(size_t)sb * SUBCAP + p] =
                make_int2(((r[k] & (BNODES-1)) << 17) | c[k], __float_as_int(v[k]));
        }
    } else {
        for (; i < e; ++i) {
            int sb = (row[i] >> BSHIFT) * NXCD + xcc;
            int p = atomicAdd(&cursor[sb * CSTRIDE], 1);
            if (p < SUBCAP) pairs[(size_t)sb * SUBCAP + p] = make_int2(((row[i] & (BNODES-1)) << 17) | col[i], __float_as_int(ev[i]));
        }
    }
}

// ---------------- bucketed reduce: counting-sort to LDS, register accumulate ----------------
__global__ __launch_bounds__(256) void reduce_kernel(const unsigned* __restrict__ hb2,
                                                     const int2* __restrict__ pairs,
                                                     const int* __restrict__ cursor,
                                                     const float2* __restrict__ bias2,
                                                     float2* __restrict__ out2, int n) {
    __shared__ int2 sp[CAP];          // sorted (col, val)
    __shared__ int hist[BNODES + 1];  // exclusive bin offsets
    __shared__ int bcur[BNODES];

    int b = blockIdx.x;
    int tid = threadIdx.x;
    int lane = tid & 63, wid = tid >> 6;

    int scnt[NXCD]; int total = 0;
    #pragma unroll
    for (int s = 0; s < NXCD; ++s) {
        int c = cursor[(b * NXCD + s) * CSTRIDE];
        scnt[s] = c > SUBCAP ? SUBCAP : c;
        total += scnt[s];
    }

    if (tid < BNODES) hist[tid] = 0;
    __syncthreads();

    // pass 1: histogram of local-row keys across 8 sub-buckets
    #pragma unroll
    for (int s = 0; s < NXCD; ++s) {
        const int2* pb = pairs + (size_t)(b * NXCD + s) * SUBCAP;
        for (int j = tid; j < scnt[s]; j += 256) atomicAdd(&hist[pb[j].x >> 17], 1);
    }
    __syncthreads();

    // exclusive scan of 64 bins (wave 0)
    if (tid < 64) {
        int v = hist[tid];
        int s = v;
        #pragma unroll
        for (int d = 1; d < 64; d <<= 1) { int t = __shfl_up(s, d); if (lane >= d) s += t; }
        hist[tid] = s - v;
        bcur[tid] = s - v;
        if (tid == 63) hist[64] = total > CAP ? CAP : total;
    }
    __syncthreads();

    // pass 2: scatter into sorted LDS order
    #pragma unroll
    for (int s = 0; s < NXCD; ++s) {
        const int2* pb = pairs + (size_t)(b * NXCD + s) * SUBCAP;
        for (int j = tid; j < scnt[s]; j += 256) {
            int2 p = pb[j];
            int rl = p.x >> 17;
            int pos = atomicAdd(&bcur[rl], 1);
            if (pos < CAP) sp[pos] = make_int2(p.x & 0x1FFFF, p.y);
        }
    }
    __syncthreads();

    // per-node register reduce
    int node0 = b * BNODES;
    for (int r = wid; r < BNODES; r += 4) {
        int node = node0 + r;
        if (node >= n) break;
        int beg = hist[r], end = hist[r + 1];
        if (beg > CAP) beg = CAP;
        if (end > CAP) end = CAP;
        float2 acc = {0.f, 0.f};
        int j = beg;
        for (; j + 8 <= end; j += 8) {
            unsigned u[8]; float v[8];
            #pragma unroll
            for (int k = 0; k < 8; ++k) {
                int2 p = sp[j + k];
                v[k] = __int_as_float(p.y);
                u[k] = hb2[(size_t)p.x * 64 + lane];
            }
            #pragma unroll
            for (int k = 0; k < 8; ++k) {
                acc.x += v[k] * __uint_as_float(u[k] << 16);
                acc.y += v[k] * __uint_as_float(u[k] & 0xFFFF0000u);
            }
        }
        for (; j < end; ++j) {
            int2 p = sp[j];
            float v = __int_as_float(p.y);
            unsigned u = hb2[(size_t)p.x * 64 + lane];
            acc.x += v * __uint_as_float(u << 16);
            acc.y += v * __uint_as_float(u & 0xFFFF0000u);
        }
        float2 bb = bias2[lane];
        f32x2 o = (f32x2){acc.x + bb.x, acc.y + bb.y};
        __builtin_nontemporal_store(o, (f32x2*)&out2[(size_t)node * 64 + lane]);
    }
}

extern "C" void kernel_launch(void* const* d_in, const int* in_sizes, int n_in,
                              void* d_out, int out_size, void* d_ws, size_t ws_size,
                              hipStream_t stream) {
    const float* x    = (const float*)d_in[0];
    const float* w    = (const float*)d_in[1];
    const float* bias = (const float*)d_in[2];
    const float* ev   = (const float*)d_in[3];
    const int*   row  = (const int*)d_in[4];
    const int*   col  = (const int*)d_in[5];
    float* out = (float*)d_out;

    int n = in_sizes[0] / D;   // 100000
    int e = in_sizes[3];       // 1600000
    int nb = (n + BNODES - 1) / BNODES;   // 1563 buckets

    // workspace layout
    unsigned* hb2    = (unsigned*)d_ws;                            // n*64 uints (25.6 MB)
    int2*     pairs  = (int2*)(hb2 + (size_t)n * 64);              // nb*8*SUBCAP int2 (25.6 MB)
    int*      cursor = (int*)(pairs + (size_t)nb * NXCD * SUBCAP); // nb*8*CSTRIDE ints (800 KB)
    unsigned short* wt_hi = (unsigned short*)(cursor + (size_t)nb * NXCD * CSTRIDE); // 32 KB
    unsigned short* wt_lo = wt_hi + D * D;                                            // 32 KB

    hipMemsetAsync(cursor, 0, (size_t)nb * NXCD * CSTRIDE * sizeof(int), stream);

    wprep_kernel<<<(D * D) / 256, 256, 0, stream>>>(w, wt_hi, wt_lo);
    gemm_kernel<<<(n + GR - 1) / GR, 256, 0, stream>>>(x, wt_hi, wt_lo, hb2, n);
    fill_kernel<<<(e + 1023) / 1024, 256, 0, stream>>>(row, col, ev, cursor, pairs, e);
    reduce_kernel<<<nb, 256, 0, stream>>>(hb2, pairs, cursor,
                                          (const float2*)bias, (float2*)out, n);
}